// Round 1
// baseline (872.820 us; speedup 1.0000x reference)
//
#include <hip/hip_runtime.h>
#include <math.h>

#define N_ROWS 16384
#define N_EXP  256
#define K_DIM  7168
#define BM 64
#define BN 128
#define BK 32
#define KITERS (K_DIM / BK)   // 224

typedef __attribute__((ext_vector_type(4))) float     f32x4;
typedef __attribute__((ext_vector_type(8))) _Float16  f16x8;
typedef __attribute__((ext_vector_type(4))) _Float16  f16x4;

// async global->LDS DMA, 16B per lane; LDS dest is wave-uniform base + lane*16
__device__ __forceinline__ void async16(const void* g, void* l) {
  __builtin_amdgcn_global_load_lds(
      (const __attribute__((address_space(1))) unsigned int*)g,
      (__attribute__((address_space(3))) unsigned int*)l, 16, 0, 0);
}

// split 8 fp32 values (scaled) into fp16 hi + fp16 residual fragments
__device__ __forceinline__ void split8(const float4 u, const float4 v, const float scale,
                                       f16x8& h, f16x8& l) {
  float f[8] = {u.x, u.y, u.z, u.w, v.x, v.y, v.z, v.w};
#pragma unroll
  for (int t = 0; t < 8; ++t) {
    const float sv = f[t] * scale;
    const _Float16 hh = (_Float16)sv;        // RN
    h[t] = hh;
    l[t] = (_Float16)(sv - (float)hh);       // exact fp32 residual, then RN to fp16
  }
}

// one-time W pre-split: Whi/Wlo fp16 planes of 64*W (same arithmetic as the old
// in-kernel split — numerics identical). 256*7168 elems, 4 per thread.
__global__ __launch_bounds__(256) void wsplit_kernel(const float* __restrict__ W,
                                                     _Float16* __restrict__ Whi,
                                                     _Float16* __restrict__ Wlo) {
  const int idx = blockIdx.x * 256 + threadIdx.x;   // 458752 threads total
  const float4 v = ((const float4*)W)[idx];
  float f[4] = {v.x, v.y, v.z, v.w};
  f16x4 h, l;
#pragma unroll
  for (int t = 0; t < 4; ++t) {
    const float sv = f[t] * 64.0f;
    const _Float16 hh = (_Float16)sv;
    h[t] = hh;
    l[t] = (_Float16)(sv - (float)hh);
  }
  ((f16x4*)Whi)[idx] = h;
  ((f16x4*)Wlo)[idx] = l;
}

// C[m][e] = sigmoid( (1/1024) * sum_k (16*x[m][k]) * (64*W[e][k]) ), fp16-split 3-term MFMA.
// X LDS: row-major [row][32 floats], 16B chunk j of row r at slot j^(r&7) (2-way, free).
// W LDS: chunk-major fp16 [4 k-chunks][128 rows][8 halves] — frag read is 2-way per
//   16-lane quarter (rows stride 16B), global_load_lds-linear.
// Double-buffered, counted vmcnt(6) (never 0 in steady state) + raw s_barrier:
//   prefetch of tile k+1 stays in flight across the barrier (T3-minimum 2-phase).
__global__ __launch_bounds__(256) void gemm_sig_kernel(const float* __restrict__ X,
                                                       const _Float16* __restrict__ Whi,
                                                       const _Float16* __restrict__ Wlo,
                                                       float* __restrict__ S) {
  __shared__ __align__(16) float    sX[2][BM * BK];    // 2 x 8 KB
  __shared__ __align__(16) _Float16 sWh[2][BN * BK];   // 2 x 8 KB
  __shared__ __align__(16) _Float16 sWl[2][BN * BK];   // 2 x 8 KB
  const int tid  = threadIdx.x;
  const int lane = tid & 63;
  const int wave = tid >> 6;
  const int wr   = wave & 1;      // row half: 32 rows
  const int wc   = wave >> 1;     // col half: 64 cols
  const int ml   = lane & 15;
  const int quad = lane >> 4;

  // col-major grid mapping: blocks i and i+256 share the X row-stripe AND land on
  // the same XCD (i%8 == (i+256)%8), co-resident at 2 blocks/CU -> L2-shared X.
  const int    rowBlk  = blockIdx.x & 255;
  const int    colBlk  = blockIdx.x >> 8;
  const size_t rowBase = (size_t)rowBlk * BM;
  const int    colBase = colBlk * BN;

  f32x4 acc[2][4];
#pragma unroll
  for (int a = 0; a < 2; ++a)
#pragma unroll
    for (int b = 0; b < 4; ++b) acc[a][b] = (f32x4){0.f, 0.f, 0.f, 0.f};

  // stage one K-tile: 6 global_load_lds per thread (X:2, Whi:2, Wlo:2)
  auto stage = [&](int buf, int kb) {
    const int kOff = kb * BK;
#pragma unroll
    for (int i = 0; i < 2; ++i) {
      const int slot = i * 256 + tid;
      const int r = slot >> 3, c7 = slot & 7;
      const int j = c7 ^ (r & 7);
      async16(X + (rowBase + (size_t)r) * K_DIM + (kOff + j * 4), &sX[buf][slot * 4]);
    }
#pragma unroll
    for (int i = 0; i < 2; ++i) {
      const int slot = i * 256 + tid;                 // slot = c*128 + r
      const int c = slot >> 7, r = slot & 127;
      const size_t g = (size_t)(colBase + r) * K_DIM + (size_t)(kOff + c * 8);
      async16(Whi + g, &sWh[buf][slot * 8]);          // LDS halves offset = slot*8 (linear)
      async16(Wlo + g, &sWl[buf][slot * 8]);
    }
  };

  stage(0, 0);

  for (int kb = 0; kb < KITERS; ++kb) {
    const int cur = kb & 1;
    if (kb + 1 < KITERS) {
      stage(cur ^ 1, kb + 1);                          // 6 more in flight (12 total)
      asm volatile("s_waitcnt vmcnt(6)" ::: "memory"); // oldest 6 (= current tile) done
    } else {
      asm volatile("s_waitcnt vmcnt(0)" ::: "memory");
    }
    __builtin_amdgcn_s_barrier();                      // raw barrier: no vmcnt(0) drain
    asm volatile("" ::: "memory");

    // fragments: A[m=lane&15][k=quad*8+j], B[n=lane&15][k=quad*8+j] (m89/m91 layout)
    f16x8 ah[2], al[2], bh[4], bl[4];
#pragma unroll
    for (int tm = 0; tm < 2; ++tm) {
      const int row = wr * 32 + tm * 16 + ml;
      const int sw  = row & 7;
      const float4 u = *(const float4*)&sX[cur][(row * 8 + ((quad * 2)     ^ sw)) * 4];
      const float4 v = *(const float4*)&sX[cur][(row * 8 + ((quad * 2 + 1) ^ sw)) * 4];
      split8(u, v, 16.0f, ah[tm], al[tm]);
    }
#pragma unroll
    for (int tn = 0; tn < 4; ++tn) {
      const int row = wc * 64 + tn * 16 + ml;
      const int off = quad * (BN * 8) + row * 8;       // chunk-plane stride = 1024 halves
      bh[tn] = *(const f16x8*)&sWh[cur][off];
      bl[tn] = *(const f16x8*)&sWl[cur][off];
    }

#pragma unroll
    for (int tm = 0; tm < 2; ++tm)
#pragma unroll
      for (int tn = 0; tn < 4; ++tn) {
        acc[tm][tn] = __builtin_amdgcn_mfma_f32_16x16x32_f16(ah[tm], bh[tn], acc[tm][tn], 0, 0, 0);
        acc[tm][tn] = __builtin_amdgcn_mfma_f32_16x16x32_f16(ah[tm], bl[tn], acc[tm][tn], 0, 0, 0);
        acc[tm][tn] = __builtin_amdgcn_mfma_f32_16x16x32_f16(al[tm], bh[tn], acc[tm][tn], 0, 0, 0);
      }

    asm volatile("" ::: "memory");
    __builtin_amdgcn_s_barrier();   // all waves done reading buf[cur] before next overwrite
  }

  // epilogue: descale + sigmoid, store scores. C/D: col=lane&15, row=(lane>>4)*4+reg
  const float inv = 1.0f / 1024.0f;
#pragma unroll
  for (int tm = 0; tm < 2; ++tm)
#pragma unroll
    for (int tn = 0; tn < 4; ++tn)
#pragma unroll
      for (int rg = 0; rg < 4; ++rg) {
        const size_t r = rowBase + wr * 32 + tm * 16 + quad * 4 + rg;
        const int    c = colBase + wc * 64 + tn * 16 + ml;
        const float  z = acc[tm][tn][rg] * inv;
        S[r * N_EXP + c] = 1.0f / (1.0f + __expf(-z));
      }
}

// one wave per row: group top-2 sums -> top-4 groups -> flat top-8 -> normalized weights
__global__ __launch_bounds__(256) void route_kernel(const float* __restrict__ S,
                                                    const float* __restrict__ bias,
                                                    float* __restrict__ outw,
                                                    float* __restrict__ outi) {
  const int lane = threadIdx.x & 63;
  const int row  = blockIdx.x * 4 + (threadIdx.x >> 6);

  const float4 v4 = ((const float4*)(S + (size_t)row * N_EXP))[lane];
  const float4 b4 = ((const float4*)bias)[lane];
  float vals[4] = {v4.x, v4.y, v4.z, v4.w};                  // original (sigmoid)
  float s[4]    = {v4.x + b4.x, v4.y + b4.y, v4.z + b4.z, v4.w + b4.w};

  // per-lane top2 of its 4 selection scores
  float a  = fmaxf(s[0], s[1]), b_ = fminf(s[0], s[1]);
  float c  = fmaxf(s[2], s[3]), d  = fminf(s[2], s[3]);
  float t1 = fmaxf(a, c);
  float t2 = fmaxf(fminf(a, c), (a > c) ? b_ : d);
  // merge top2 across 8-lane group segments (group = 32 experts = 8 lanes)
#pragma unroll
  for (int off = 1; off < 8; off <<= 1) {
    const float o1 = __shfl_xor(t1, off);
    const float o2 = __shfl_xor(t2, off);
    const float n1 = fmaxf(t1, o1);
    const float n2 = fmaxf(fminf(t1, o1), (t1 > o1) ? t2 : o2);
    t1 = n1; t2 = n2;
  }
  const float gsum = t1 + t2;
  const int g = lane >> 3;
  float gs[8];
#pragma unroll
  for (int j = 0; j < 8; ++j) gs[j] = __shfl(gsum, j * 8);
  int rank = 0;
#pragma unroll
  for (int j = 0; j < 8; ++j)
    rank += (gs[j] > gs[g]) || (gs[j] == gs[g] && j < g);
  if (rank >= 4) { s[0] = s[1] = s[2] = s[3] = -INFINITY; }

  // flat top-8: wave argmax with (value desc, index asc) tie-break, 8 iterations
  float topw[8]; int topi[8];
  float wsum = 0.0f;
  const int col0 = lane * 4;
#pragma unroll
  for (int k = 0; k < 8; ++k) {
    float bv = s[0]; int bi = col0;
    if (s[1] > bv) { bv = s[1]; bi = col0 + 1; }
    if (s[2] > bv) { bv = s[2]; bi = col0 + 2; }
    if (s[3] > bv) { bv = s[3]; bi = col0 + 3; }
#pragma unroll
    for (int off = 32; off > 0; off >>= 1) {
      const float ov = __shfl_xor(bv, off);
      const int   oi = __shfl_xor(bi, off);
      if (ov > bv || (ov == bv && oi < bi)) { bv = ov; bi = oi; }
    }
    const int slot = bi & 3, owner = bi >> 2;
    const float cand = (slot == 0) ? vals[0] : (slot == 1) ? vals[1] : (slot == 2) ? vals[2] : vals[3];
    const float wv = __shfl(cand, owner);
    topw[k] = wv; topi[k] = bi; wsum += wv;
    if (lane == owner) {
      if      (slot == 0) s[0] = -INFINITY;
      else if (slot == 1) s[1] = -INFINITY;
      else if (slot == 2) s[2] = -INFINITY;
      else                s[3] = -INFINITY;
    }
  }
  const float sc = 2.5f / wsum;
  if (lane == 0) {
#pragma unroll
    for (int k = 0; k < 8; ++k) {
      outw[(size_t)row * 8 + k] = topw[k] * sc;
      outi[(size_t)row * 8 + k] = (float)topi[k];   // indices as float (flat fp32 compare)
    }
  }
}

extern "C" void kernel_launch(void* const* d_in, const int* in_sizes, int n_in,
                              void* d_out, int out_size, void* d_ws, size_t ws_size,
                              hipStream_t stream) {
  (void)in_sizes; (void)n_in; (void)out_size; (void)ws_size;
  const float* X  = (const float*)d_in[0];
  const float* Wt = (const float*)d_in[1];
  const float* b  = (const float*)d_in[2];

  // workspace layout: scores 16.78 MB | Whi 3.67 MB | Wlo 3.67 MB  (24.1 MB total)
  float*    scores = (float*)d_ws;
  _Float16* Whi    = (_Float16*)((char*)d_ws + (size_t)N_ROWS * N_EXP * 4);
  _Float16* Wlo    = Whi + (size_t)N_EXP * K_DIM;
  float* outw = (float*)d_out;                        // [N,8] weights
  float* outi = outw + (size_t)N_ROWS * 8;            // [N,8] indices (as float)

  wsplit_kernel<<<(N_EXP * K_DIM / 4) / 256, 256, 0, stream>>>(Wt, Whi, Wlo);
  gemm_sig_kernel<<<(N_ROWS / BM) * (N_EXP / BN), 256, 0, stream>>>(X, Whi, Wlo, scores);
  route_kernel<<<N_ROWS / 4, 256, 0, stream>>>(scores, b, outw, outi);
}